// Round 7
// baseline (164.577 us; speedup 1.0000x reference)
//
#include <hip/hip_runtime.h>
#include <hip/hip_bf16.h>

#define HH 1024
#define LL 512
#define NT 16              // 512/32 row-tiles
#define NTRI 136           // NT*(NT+1)/2 triangular tiles

typedef __attribute__((ext_vector_type(8))) short bf16x8;
typedef __attribute__((ext_vector_type(4))) float f32x4;

static constexpr float C_EXP = 2.8853900817779268f; // 2*log2(e)

static __device__ __forceinline__ ushort f2bf(float f) {
    unsigned u = __builtin_bit_cast(unsigned, f);
    u += 0x7fffu + ((u >> 16) & 1u);   // round-to-nearest-even
    return (ushort)(u >> 16);
}

// pack 8 fp32 -> 8 bf16 (RNE) as uint4
static __device__ __forceinline__ uint4 pack8(float4 a, float4 b) {
    union { uint4 u; __hip_bfloat162 h[4]; } r;
    r.h[0] = __float22bfloat162_rn(make_float2(a.x, a.y));
    r.h[1] = __float22bfloat162_rn(make_float2(a.z, a.w));
    r.h[2] = __float22bfloat162_rn(make_float2(b.x, b.y));
    r.h[3] = __float22bfloat162_rn(make_float2(b.z, b.w));
    return r.u;
}

// ---------------------------------------------------------------------------
// Kernel 0: fp32->bf16 convert (lm 1MB, W1 4MB) + wsum[c] = sum_h W2[c,h].
//   B16[n][k] = bf16(W1[(n&1023)*2048 + (n>>10)*1024 + k])   n<1024: Wa, else Wb
// ---------------------------------------------------------------------------
__global__ __launch_bounds__(256) void convert_kernel(
    const float* __restrict__ lm, const float* __restrict__ W1,
    const float* __restrict__ W2,
    ushort* __restrict__ lm16, ushort* __restrict__ B16, float* __restrict__ wsum)
{
    const int b = blockIdx.x;
    if (b == 1280) {
        const int tid = threadIdx.x;
        if (tid < 128) {
            const int c = tid >> 6, l = tid & 63;
            float s = 0.f;
            for (int q = l; q < 256; q += 64) {
                const float4 v = *(const float4*)&W2[c * HH + q * 4];
                s += v.x + v.y + v.z + v.w;
            }
#pragma unroll
            for (int off = 32; off; off >>= 1) s += __shfl_down(s, off, 64);
            if (l == 0) wsum[c] = s;
        }
        return;
    }
    const int q = b * 256 + threadIdx.x;            // 8-elem group
    if (q < 65536) {                                // lm: 512*1024/8
        const float4 a = *(const float4*)&lm[q * 8];
        const float4 c = *(const float4*)&lm[q * 8 + 4];
        ((uint4*)lm16)[q] = pack8(a, c);
    } else {
        const int p = q - 65536;                    // 0..262143
        const int n = p >> 7, k8 = (p & 127) * 8;
        const float* src = &W1[(n & 1023) * 2048 + (n >> 10) * 1024 + k8];
        ((uint4*)B16)[p] = pack8(*(const float4*)src, *(const float4*)(src + 4));
    }
}

// ---------------------------------------------------------------------------
// Kernel 1: barrier-free, LDS-free MFMA projection.
// One wave = one 16m x 16n tile over full K=1024 (32 MFMA iters). A/B frags
// loaded DIRECTLY from global (row-major matches frag layout: row=lane&15,
// k=(lane>>4)*8 -> per-row 64B contiguous segments, coalesced). No barriers.
// Epilogue: Eab[m][n] = packed(bf16(exp2(C*(accA+b1))), bf16(exp2(C*accB)))
// written componentwise (half 0 by n<1024 waves, half 1 by n>=1024 waves).
// Grid 1024 blocks (4096 waves = 4/SIMD). XCD swizzle: xcd=b&7 owns a 0.5MB
// B16 n-slice; lm16 re-reads are L1/L2-served.
// ---------------------------------------------------------------------------
__global__ __launch_bounds__(256, 4) void proj_mfma_kernel(
    const ushort* __restrict__ lm16, const ushort* __restrict__ B16,
    const float* __restrict__ b1, uint* __restrict__ Eab)
{
    const int tid  = threadIdx.x;
    const int lane = tid & 63;
    const int w    = tid >> 6;
    const int b    = blockIdx.x;
    const int xcd  = b & 7, s = b >> 3;
    const int m_tile = s >> 2;                       // 0..31
    const int n_tile = xcd * 16 + (s & 3) * 4 + w;   // 0..127
    const int mbase = m_tile * 16;
    const int nbase = n_tile * 16;

    const int frow = lane & 15;
    const int q8   = (lane >> 4) * 8;

    const ushort* ap = &lm16[(mbase + frow) * HH + q8];
    const ushort* bp = &B16[(nbase + frow) * HH + q8];

    f32x4 acc = {0.f, 0.f, 0.f, 0.f};
#pragma unroll 8
    for (int kb = 0; kb < HH; kb += 32) {
        const bf16x8 a  = *(const bf16x8*)(ap + kb);
        const bf16x8 bb = *(const bf16x8*)(bp + kb);
        acc = __builtin_amdgcn_mfma_f32_16x16x32_bf16(a, bb, acc, 0, 0, 0);
    }

    // D mapping: col=lane&15 (n), row=(lane>>4)*4+reg (m)
    const int col  = lane & 15;
    const int rq   = (lane >> 4) * 4;
    const int n_g  = nbase + col;
    const int m0   = mbase + rq;
    const int half = n_g >> 10;              // wave-uniform (16-aligned tiles)
    const int nn   = n_g & 1023;
    const float bb1 = half ? 0.f : b1[n_g & 1023];
    ushort* eo = (ushort*)Eab;
#pragma unroll
    for (int r = 0; r < 4; ++r) {
        const float e = __builtin_amdgcn_exp2f(C_EXP * (acc[r] + bb1));
        eo[((m0 + r) * HH + nn) * 2 + half] = f2bf(e);
    }
}

// ---------------------------------------------------------------------------
// Kernel 2: triangular pairwise contraction on packed bf16 (Ea,Eb).
//   u = 1/(Ea[j,h]*Eb[i,h]+1) + 1/(Ea[i,h]*Eb[j,h]+1)
//   pbuf = sum_slice u * W2[c,h]     (out = wsum + b2 - sum_z pbuf in combine)
// Block = (bi<=bj) 32x32 tile pair x one h-slice. Thread owns 2i x 2j.
// LDS ~18 KB (packed) -> 6 blocks/CU via launch_bounds(256,6); grid 136 x nz
// (nz=8 -> 1088 blocks, all co-resident). Batched rcp: 1 per 4 denominators.
// ---------------------------------------------------------------------------
__global__ __launch_bounds__(256, 6) void pair_kernel(
    const uint* __restrict__ Eab, const float* __restrict__ W2,
    float* __restrict__ pbuf, int nz)
{
    __shared__ uint jt[32][68];     // 68 mod 32 = 4: <=2-way banks, 16B-aligned
    __shared__ uint it_[32][68];
    __shared__ float w0_s[256], w1_s[256];

    const int tid = threadIdx.x;
    const int tx  = tid & 15;
    const int ty  = tid >> 4;

    int tt = blockIdx.x, bi = 0, rem = NT;          // triangular decode
    while (tt >= rem) { tt -= rem; --rem; ++bi; }
    const int bj    = bi + tt;
    const int ibase = bi * 32;
    const int jbase = bj * 32;
    const int slice = HH / nz;
    const int k0    = blockIdx.y * slice;

    {   // stage W2 slice (slice/4 float4 per channel)
        const int nf4 = slice >> 2;
        if (tid < 2 * nf4) {
            const int c = tid >= nf4, q = tid - c * nf4;
            ((float4*)(c ? w1_s : w0_s))[q] = *(const float4*)&W2[c * HH + k0 + q * 4];
        }
    }

    float acc[2][2][2] = {};  // [ii][jj][c]

    for (int kb = 0; kb < slice; kb += 64) {
        __syncthreads();
        {   // stage 2 tiles x 32 rows x 64 uint = 1024 uint4, 4/thread
            int p = tid;
#pragma unroll
            for (int it2 = 0; it2 < 4; ++it2, p += 256) {
                const int tile = p >> 9, row = (p >> 4) & 31, c4 = p & 15;
                const int rb = tile ? ibase : jbase;
                const uint4 v = *(const uint4*)&Eab[(rb + row) * HH + k0 + kb + c4 * 4];
                if (tile) *(uint4*)&it_[row][c4 * 4] = v;
                else      *(uint4*)&jt[row][c4 * 4] = v;
            }
        }
        __syncthreads();

#pragma unroll 4
        for (int h4 = 0; h4 < 16; ++h4) {
            const uint4 J0 = *(const uint4*)&jt[tx][h4 * 4];
            const uint4 J1 = *(const uint4*)&jt[tx + 16][h4 * 4];
            const uint4 I0 = *(const uint4*)&it_[ty][h4 * 4];
            const uint4 I1 = *(const uint4*)&it_[ty + 16][h4 * 4];
            const float4 w0 = *(const float4*)&w0_s[kb + h4 * 4];  // broadcast
            const float4 w1 = *(const float4*)&w1_s[kb + h4 * 4];

#define DO_H(UJ0, UJ1, UI0, UI1, W0V, W1V)                             \
            {                                                          \
                const float Aj0 = __builtin_bit_cast(float, (UJ0) << 16);          \
                const float Bj0 = __builtin_bit_cast(float, (UJ0) & 0xffff0000u);  \
                const float Aj1 = __builtin_bit_cast(float, (UJ1) << 16);          \
                const float Bj1 = __builtin_bit_cast(float, (UJ1) & 0xffff0000u);  \
                const float Ai0 = __builtin_bit_cast(float, (UI0) << 16);          \
                const float Bi0 = __builtin_bit_cast(float, (UI0) & 0xffff0000u);  \
                const float Ai1 = __builtin_bit_cast(float, (UI1) << 16);          \
                const float Bi1 = __builtin_bit_cast(float, (UI1) & 0xffff0000u);  \
                const float d00 = __builtin_fmaf(Bi0, Aj0, 1.f);       \
                const float d01 = __builtin_fmaf(Bi0, Aj1, 1.f);       \
                const float d10 = __builtin_fmaf(Bi1, Aj0, 1.f);       \
                const float d11 = __builtin_fmaf(Bi1, Aj1, 1.f);       \
                const float e00 = __builtin_fmaf(Ai0, Bj0, 1.f);       \
                const float e01 = __builtin_fmaf(Ai0, Bj1, 1.f);       \
                const float e10 = __builtin_fmaf(Ai1, Bj0, 1.f);       \
                const float e11 = __builtin_fmaf(Ai1, Bj1, 1.f);       \
                const float dp0 = d00 * d01, dp1 = d10 * d11;          \
                const float DR  = __builtin_amdgcn_rcpf(dp0 * dp1);    \
                const float dq0 = DR * dp1, dq1 = DR * dp0;            \
                const float rd00 = dq0 * d01, rd01 = dq0 * d00;        \
                const float rd10 = dq1 * d11, rd11 = dq1 * d10;        \
                const float ep0 = e00 * e01, ep1 = e10 * e11;          \
                const float ER  = __builtin_amdgcn_rcpf(ep0 * ep1);    \
                const float eq0 = ER * ep1, eq1 = ER * ep0;            \
                const float re00 = eq0 * e01, re01 = eq0 * e00;        \
                const float re10 = eq1 * e11, re11 = eq1 * e10;        \
                const float u00 = rd00 + re00, u01 = rd01 + re01;      \
                const float u10 = rd10 + re10, u11 = rd11 + re11;      \
                acc[0][0][0] = __builtin_fmaf(u00, (W0V), acc[0][0][0]); \
                acc[0][0][1] = __builtin_fmaf(u00, (W1V), acc[0][0][1]); \
                acc[0][1][0] = __builtin_fmaf(u01, (W0V), acc[0][1][0]); \
                acc[0][1][1] = __builtin_fmaf(u01, (W1V), acc[0][1][1]); \
                acc[1][0][0] = __builtin_fmaf(u10, (W0V), acc[1][0][0]); \
                acc[1][0][1] = __builtin_fmaf(u10, (W1V), acc[1][0][1]); \
                acc[1][1][0] = __builtin_fmaf(u11, (W0V), acc[1][1][0]); \
                acc[1][1][1] = __builtin_fmaf(u11, (W1V), acc[1][1][1]); \
            }
            DO_H(J0.x, J1.x, I0.x, I1.x, w0.x, w1.x)
            DO_H(J0.y, J1.y, I0.y, I1.y, w0.y, w1.y)
            DO_H(J0.z, J1.z, I0.z, I1.z, w0.z, w1.z)
            DO_H(J0.w, J1.w, I0.w, I1.w, w0.w, w1.w)
#undef DO_H
        }
    }

    float* pb = pbuf + ((size_t)blockIdx.y * NTRI + blockIdx.x) * 2048;
#pragma unroll
    for (int ii = 0; ii < 2; ++ii)
#pragma unroll
        for (int jj = 0; jj < 2; ++jj) {
            const int li = ty + ii * 16, lj = tx + jj * 16;
            *(float2*)&pb[(li * 32 + lj) * 2] =
                make_float2(acc[ii][jj][0], acc[ii][jj][1]);
        }
}

// ---------------------------------------------------------------------------
// Kernel 3: combine: out = wsum[c] + b2[c] - sum_z pbuf, scatter (i,j)+(j,i).
// ---------------------------------------------------------------------------
__global__ __launch_bounds__(256) void combine_kernel(
    const float* __restrict__ pbuf, const float* __restrict__ b2,
    const float* __restrict__ wsum, float* __restrict__ out, int nz)
{
    const int idx   = blockIdx.x * 256 + threadIdx.x;   // 0 .. 136*2048-1
    const int t     = idx >> 11;
    const int local = idx & 2047;
    int tt = t, bi = 0, rem = NT;
    while (tt >= rem) { tt -= rem; --rem; ++bi; }
    const int bj = bi + tt;

    float s = 0.f;
    for (int z = 0; z < nz; ++z)
        s += pbuf[((size_t)z * NTRI + t) * 2048 + local];

    const int li = local >> 6;
    const int lj = (local >> 1) & 31;
    const int c  = local & 1;
    const float v = wsum[c] + b2[c] - s;

    const int i = bi * 32 + li;
    const int j = bj * 32 + lj;
    out[(i * LL + j) * 2 + c] = v;
    out[(j * LL + i) * 2 + c] = v;   // diagonal tiles: same-value rewrite, benign
}

extern "C" void kernel_launch(void* const* d_in, const int* in_sizes, int n_in,
                              void* d_out, int out_size, void* d_ws, size_t ws_size,
                              hipStream_t stream)
{
    const float* lm = (const float*)d_in[0];
    const float* W1 = (const float*)d_in[1];
    const float* b1 = (const float*)d_in[2];
    const float* W2 = (const float*)d_in[3];
    const float* b2 = (const float*)d_in[4];
    float* out = (float*)d_out;

    char* ws = (char*)d_ws;
    uint*   Eab  = (uint*)ws;                            // 2 MB packed (Ea,Eb)
    ushort* lm16 = (ushort*)(ws + (2u << 20));           // 1 MB
    ushort* B16  = (ushort*)(ws + (3u << 20));           // 4 MB
    float*  wsum = (float*)(ws + (7u << 20));            // 256 B
    float*  pbuf = (float*)(ws + (7u << 20) + 256);      // nz * 1.11 MB

    const size_t base = (7u << 20) + 256;
    int nz = 8;
    while (nz > 2 && base + (size_t)nz * NTRI * 2048 * 4 > ws_size) nz >>= 1;

    convert_kernel<<<1281, 256, 0, stream>>>(lm, W1, W2, lm16, B16, wsum);
    proj_mfma_kernel<<<1024, 256, 0, stream>>>(lm16, B16, b1, Eab);
    pair_kernel<<<dim3(NTRI, nz), 256, 0, stream>>>(Eab, W2, pbuf, nz);
    combine_kernel<<<(NTRI * 2048) / 256, 256, 0, stream>>>(pbuf, b2, wsum, out, nz);
}